// Round 1
// baseline (1848.706 us; speedup 1.0000x reference)
//
#include <hip/hip_runtime.h>
#include <math.h>

// Sizes: B=16, H=128, W=128, C=64, MODES=16, SCHMIDT=8, N_LAYERS=4
// h buffer: 16*128*128*64 = 16,777,216 floats (67 MB), updated in place per layer.

#define TWO_PI_128 0.049087385212340517f   // 2*pi/128
#define PI_4       0.78539816339744831f    // pi/4

__device__ __forceinline__ float gelu_f(float v) {
  float v2 = v * v;
  float u = 0.7978845608028654f * v * fmaf(0.044715f, v2, 1.0f);
  return 0.5f * v * (1.0f + tanhf(u));
}

// h[pix][c] = sum_k x[pix][k] * w[k][c] + b[c]
__global__ __launch_bounds__(256) void k_fc_in(const float* __restrict__ x,
    const float* __restrict__ w, const float* __restrict__ b,
    float* __restrict__ h) {
  int idx = blockIdx.x * 256 + threadIdx.x;   // over NPIX*64
  int pix = idx >> 6, c = idx & 63;
  float acc = b[c];
  acc = fmaf(x[pix * 3 + 0], w[c], acc);
  acc = fmaf(x[pix * 3 + 1], w[64 + c], acc);
  acc = fmaf(x[pix * 3 + 2], w[128 + c], acc);
  h[idx] = acc;
}

// Fold Schmidt sum + 1/sqrt(8) + 1/(128*128) into complex weight,
// laid out for GEMM: Br/Bi[(n*64+c)*1024 + (m*64+o)]
__global__ __launch_bounds__(256) void k_prep(const float* __restrict__ wr,
    const float* __restrict__ wi, float* __restrict__ Br, float* __restrict__ Bi) {
  int t = blockIdx.x * 256 + threadIdx.x;     // linear over (m,n,c,o), o innermost
  int o = t & 63, c = (t >> 6) & 63, n = (t >> 12) & 15, m = t >> 16;
  const float4* pr = (const float4*)(wr) + (size_t)t * 2;
  float4 a = pr[0], d = pr[1];
  float sr = ((a.x + a.y) + (a.z + a.w)) + ((d.x + d.y) + (d.z + d.w));
  const float4* pi = (const float4*)(wi) + (size_t)t * 2;
  a = pi[0]; d = pi[1];
  float si = ((a.x + a.y) + (a.z + a.w)) + ((d.x + d.y) + (d.z + d.w));
  const float scale = 0.35355339059327373f / 16384.0f;  // 1/(sqrt(8)*128*128)
  int k = n * 64 + c, j = m * 64 + o;
  Br[k * 1024 + j] = sr * scale;
  Bi[k * 1024 + j] = si * scale;
}

// Forward truncated DFT along y (W axis): A1[b][x][ky][c], ky<16
__global__ __launch_bounds__(256) void k_dft_y(const float* __restrict__ h,
                                               float2* __restrict__ A1) {
  __shared__ float sh[128 * 64];
  int bx = blockIdx.x;                        // b*128 + x
  const float* src = h + (size_t)bx * 8192;
  for (int i = threadIdx.x; i < 8192; i += 256) sh[i] = src[i];
  __syncthreads();
  int c = threadIdx.x & 63, kg = threadIdx.x >> 6;
  float cs[4], sn[4], wr_[4], wi_[4], sr[4], si[4];
  #pragma unroll
  for (int q = 0; q < 4; ++q) {
    int ky = kg + 4 * q;
    __sincosf(-TWO_PI_128 * (float)ky, &sn[q], &cs[q]);
    wr_[q] = 1.f; wi_[q] = 0.f; sr[q] = 0.f; si[q] = 0.f;
  }
  for (int y = 0; y < 128; ++y) {
    float hv = sh[y * 64 + c];
    #pragma unroll
    for (int q = 0; q < 4; ++q) {
      sr[q] = fmaf(hv, wr_[q], sr[q]);
      si[q] = fmaf(hv, wi_[q], si[q]);
      float nw = wr_[q] * cs[q] - wi_[q] * sn[q];
      wi_[q] = fmaf(wi_[q], cs[q], wr_[q] * sn[q]);
      wr_[q] = nw;
    }
  }
  #pragma unroll
  for (int q = 0; q < 4; ++q) {
    int ky = kg + 4 * q;
    A1[((size_t)bx * 16 + ky) * 64 + c] = make_float2(sr[q], si[q]);
  }
}

// Forward truncated DFT along x (H axis): rows (b*16+kx), cols (ky*64+c)
__global__ __launch_bounds__(256) void k_dft_x(const float2* __restrict__ A1,
    float* __restrict__ Ar, float* __restrict__ Ai) {
  __shared__ float2 sh[128 * 32];
  int b = blockIdx.x, ky = blockIdx.y, ch = blockIdx.z;
  int c0 = ch * 32;
  for (int i = threadIdx.x; i < 4096; i += 256) {
    int xx = i >> 5, cl = i & 31;
    sh[i] = A1[(((size_t)b * 128 + xx) * 16 + ky) * 64 + c0 + cl];
  }
  __syncthreads();
  int cl = threadIdx.x & 31, kxg = threadIdx.x >> 5;
  float cs[2], sn[2], wr_[2], wi_[2], sr[2], si[2];
  #pragma unroll
  for (int q = 0; q < 2; ++q) {
    int kx = kxg + 8 * q;
    __sincosf(-TWO_PI_128 * (float)kx, &sn[q], &cs[q]);
    wr_[q] = 1.f; wi_[q] = 0.f; sr[q] = 0.f; si[q] = 0.f;
  }
  for (int xx = 0; xx < 128; ++xx) {
    float2 v = sh[xx * 32 + cl];
    #pragma unroll
    for (int q = 0; q < 2; ++q) {
      sr[q] = fmaf(v.x, wr_[q], sr[q]); sr[q] = fmaf(-v.y, wi_[q], sr[q]);
      si[q] = fmaf(v.x, wi_[q], si[q]); si[q] = fmaf(v.y, wr_[q], si[q]);
      float nw = wr_[q] * cs[q] - wi_[q] * sn[q];
      wi_[q] = fmaf(wi_[q], cs[q], wr_[q] * sn[q]);
      wr_[q] = nw;
    }
  }
  #pragma unroll
  for (int q = 0; q < 2; ++q) {
    int kx = kxg + 8 * q;
    int row = b * 16 + kx, col = ky * 64 + c0 + cl;
    Ar[row * 1024 + col] = sr[q];
    Ai[row * 1024 + col] = si[q];
  }
}

// Complex GEMM: C[256][1024] = A[256][1024] * B[1024][1024], K split in 2 (blockIdx.z)
__global__ __launch_bounds__(256) void k_gemm(const float* __restrict__ Ar,
    const float* __restrict__ Ai, const float* __restrict__ Br,
    const float* __restrict__ Bi, float2* __restrict__ Cp) {
  __shared__ float2 As[32][33];
  __shared__ float2 Bs[32][34];
  int tx = threadIdx.x & 15, ty = threadIdx.x >> 4;
  int row0 = blockIdx.y * 32, col0 = blockIdx.x * 32, kbase = blockIdx.z * 512;
  float cr00 = 0, cr01 = 0, cr10 = 0, cr11 = 0;
  float ci00 = 0, ci01 = 0, ci10 = 0, ci11 = 0;
  for (int kt = 0; kt < 512; kt += 32) {
    int k0 = kbase + kt;
    for (int i = threadIdx.x; i < 1024; i += 256) {
      int r = i >> 5, kk = i & 31;
      int gi = (row0 + r) * 1024 + k0 + kk;
      As[r][kk] = make_float2(Ar[gi], Ai[gi]);
    }
    for (int i = threadIdx.x; i < 1024; i += 256) {
      int kk = i >> 5, j = i & 31;
      int gi = (k0 + kk) * 1024 + col0 + j;
      Bs[kk][j] = make_float2(Br[gi], Bi[gi]);
    }
    __syncthreads();
    #pragma unroll 8
    for (int kk = 0; kk < 32; ++kk) {
      float2 a0 = As[ty * 2][kk], a1 = As[ty * 2 + 1][kk];
      float2 b0 = Bs[kk][tx * 2], b1 = Bs[kk][tx * 2 + 1];
      cr00 = fmaf(a0.x, b0.x, cr00); cr00 = fmaf(-a0.y, b0.y, cr00);
      ci00 = fmaf(a0.x, b0.y, ci00); ci00 = fmaf(a0.y, b0.x, ci00);
      cr01 = fmaf(a0.x, b1.x, cr01); cr01 = fmaf(-a0.y, b1.y, cr01);
      ci01 = fmaf(a0.x, b1.y, ci01); ci01 = fmaf(a0.y, b1.x, ci01);
      cr10 = fmaf(a1.x, b0.x, cr10); cr10 = fmaf(-a1.y, b0.y, cr10);
      ci10 = fmaf(a1.x, b0.y, ci10); ci10 = fmaf(a1.y, b0.x, ci10);
      cr11 = fmaf(a1.x, b1.x, cr11); cr11 = fmaf(-a1.y, b1.y, cr11);
      ci11 = fmaf(a1.x, b1.y, ci11); ci11 = fmaf(a1.y, b1.x, ci11);
    }
    __syncthreads();
  }
  int r = row0 + ty * 2, jj = col0 + tx * 2;
  size_t base = ((size_t)blockIdx.z * 256 + r) * 1024 + jj;
  Cp[base]        = make_float2(cr00, ci00);
  Cp[base + 1]    = make_float2(cr01, ci01);
  Cp[base + 1024] = make_float2(cr10, ci10);
  Cp[base + 1025] = make_float2(cr11, ci11);
}

// Inverse DFT along the W-frequency axis m -> y. Sums the two K-split partials.
// T layout: [b][y][kx][c]
__global__ __launch_bounds__(256) void k_ifft_y(const float2* __restrict__ Cp,
                                                float2* __restrict__ T) {
  __shared__ float2 Cl[1024];
  int b = blockIdx.x >> 4, kx = blockIdx.x & 15;
  int row = b * 16 + kx;
  for (int i = threadIdx.x; i < 1024; i += 256) {
    float2 u = Cp[(size_t)row * 1024 + i];
    float2 v = Cp[(size_t)(256 + row) * 1024 + i];
    Cl[i] = make_float2(u.x + v.x, u.y + v.y);
  }
  __syncthreads();
  int c = threadIdx.x & 63, yg = threadIdx.x >> 6;
  for (int y = yg; y < 128; y += 4) {
    float snv, csv;
    __sincosf(TWO_PI_128 * (float)y, &snv, &csv);
    float wr_ = 1.f, wi_ = 0.f, sr = 0.f, si = 0.f;
    #pragma unroll
    for (int ky = 0; ky < 16; ++ky) {
      float2 v = Cl[ky * 64 + c];
      sr = fmaf(v.x, wr_, sr); sr = fmaf(-v.y, wi_, sr);
      si = fmaf(v.x, wi_, si); si = fmaf(v.y, wr_, si);
      float nw = wr_ * csv - wi_ * snv;
      wi_ = fmaf(wi_, csv, wr_ * snv);
      wr_ = nw;
    }
    T[(((size_t)b * 128 + y) * 16 + kx) * 64 + c] = make_float2(sr, si);
  }
}

// Fused: inverse DFT along kx -> x (real part) + pointwise h@ww + wb + gelu.
// Block (b,y): reads/writes exactly the h elements at fixed (b,y) -> in-place safe.
__global__ __launch_bounds__(256) void k_layer_out(const float* hin,
    const float2* __restrict__ T, const float* __restrict__ ww,
    const float* __restrict__ wb, float* hout) {
  __shared__ alignas(16) float hl[128 * 68];
  __shared__ alignas(16) float wwT[64 * 68];
  __shared__ float2 Tl[1024];
  int b = blockIdx.x >> 7, y = blockIdx.x & 127;
  for (int i = threadIdx.x; i < 8192; i += 256) {
    int xx = i >> 6, c = i & 63;
    hl[xx * 68 + c] = hin[(((size_t)b * 128 + xx) * 128 + y) * 64 + c];
  }
  for (int i = threadIdx.x; i < 4096; i += 256) {
    int k = i >> 6, c = i & 63;
    wwT[c * 68 + k] = ww[i];
  }
  for (int i = threadIdx.x; i < 1024; i += 256)
    Tl[i] = T[((size_t)b * 128 + y) * 1024 + i];
  __syncthreads();
  int ct = threadIdx.x & 15, xg = threadIdx.x >> 4;   // c = ct+16*cc, x = xg+16*j
  float acc[8][4];
  #pragma unroll
  for (int cc = 0; cc < 4; ++cc) {
    float bv = wb[ct + 16 * cc];
    #pragma unroll
    for (int j = 0; j < 8; ++j) acc[j][cc] = bv;
  }
  // x1: real part of sum_kx T[kx][c] * e^{+2pi i kx x/128}
  for (int kx = 0; kx < 16; ++kx) {
    float tr[4], ti[4];
    #pragma unroll
    for (int cc = 0; cc < 4; ++cc) {
      float2 v = Tl[kx * 64 + ct + 16 * cc];
      tr[cc] = v.x; ti[cc] = v.y;
    }
    float s0v, c0v, sst, cst;
    __sincosf(TWO_PI_128 * (float)(kx * xg), &s0v, &c0v);
    __sincosf(PI_4 * (float)kx, &sst, &cst);
    float wr_ = c0v, wi_ = s0v;
    #pragma unroll
    for (int j = 0; j < 8; ++j) {
      #pragma unroll
      for (int cc = 0; cc < 4; ++cc) {
        acc[j][cc] = fmaf(tr[cc], wr_, acc[j][cc]);
        acc[j][cc] = fmaf(-ti[cc], wi_, acc[j][cc]);
      }
      float nw = wr_ * cst - wi_ * sst;
      wi_ = fmaf(wi_, cst, wr_ * sst);
      wr_ = nw;
    }
  }
  // x2: h @ ww
  for (int kq = 0; kq < 64; kq += 4) {
    float4 wv[4];
    #pragma unroll
    for (int cc = 0; cc < 4; ++cc)
      wv[cc] = *(const float4*)&wwT[(ct + 16 * cc) * 68 + kq];
    #pragma unroll
    for (int j = 0; j < 8; ++j) {
      float4 hv = *(const float4*)&hl[(xg + 16 * j) * 68 + kq];
      #pragma unroll
      for (int cc = 0; cc < 4; ++cc) {
        acc[j][cc] = fmaf(hv.x, wv[cc].x, acc[j][cc]);
        acc[j][cc] = fmaf(hv.y, wv[cc].y, acc[j][cc]);
        acc[j][cc] = fmaf(hv.z, wv[cc].z, acc[j][cc]);
        acc[j][cc] = fmaf(hv.w, wv[cc].w, acc[j][cc]);
      }
    }
  }
  #pragma unroll
  for (int j = 0; j < 8; ++j) {
    int xx = xg + 16 * j;
    size_t base = (((size_t)b * 128 + xx) * 128 + y) * 64 + ct;
    #pragma unroll
    for (int cc = 0; cc < 4; ++cc)
      hout[base + 16 * cc] = gelu_f(acc[j][cc]);
  }
}

// Fused fc1 + gelu + fc2
__global__ __launch_bounds__(256) void k_final(const float* __restrict__ h,
    const float* __restrict__ w1, const float* __restrict__ b1,
    const float* __restrict__ w2, const float* __restrict__ b2,
    float* __restrict__ out) {
  __shared__ alignas(16) float w1T[128 * 68];
  __shared__ alignas(16) float hl2[32 * 68];
  __shared__ float b1s[128];
  __shared__ float w2s[128];
  for (int i = threadIdx.x; i < 8192; i += 256) {
    int k = i >> 7, j = i & 127;
    w1T[j * 68 + k] = w1[i];
  }
  if (threadIdx.x < 128) {
    b1s[threadIdx.x] = b1[threadIdx.x];
    w2s[threadIdx.x] = w2[threadIdx.x];
  }
  float b2v = b2[0];
  int jt = threadIdx.x & 31, rg = threadIdx.x >> 5;   // j = jt+32*cc, r = rg+8*i
  for (int chunk = 0; chunk < 8; ++chunk) {
    int r0 = blockIdx.x * 256 + chunk * 32;
    __syncthreads();
    for (int i = threadIdx.x; i < 2048; i += 256) {
      int r = i >> 6, c = i & 63;
      hl2[r * 68 + c] = h[(size_t)(r0 + r) * 64 + c];
    }
    __syncthreads();
    float t[4][4];
    #pragma unroll
    for (int i = 0; i < 4; ++i)
      #pragma unroll
      for (int cc = 0; cc < 4; ++cc)
        t[i][cc] = b1s[jt + 32 * cc];
    for (int kq = 0; kq < 64; kq += 4) {
      float4 wv[4];
      #pragma unroll
      for (int cc = 0; cc < 4; ++cc)
        wv[cc] = *(const float4*)&w1T[(jt + 32 * cc) * 68 + kq];
      #pragma unroll
      for (int i = 0; i < 4; ++i) {
        float4 hv = *(const float4*)&hl2[(rg + 8 * i) * 68 + kq];
        #pragma unroll
        for (int cc = 0; cc < 4; ++cc) {
          t[i][cc] = fmaf(hv.x, wv[cc].x, t[i][cc]);
          t[i][cc] = fmaf(hv.y, wv[cc].y, t[i][cc]);
          t[i][cc] = fmaf(hv.z, wv[cc].z, t[i][cc]);
          t[i][cc] = fmaf(hv.w, wv[cc].w, t[i][cc]);
        }
      }
    }
    #pragma unroll
    for (int i = 0; i < 4; ++i) {
      float part = 0.f;
      #pragma unroll
      for (int cc = 0; cc < 4; ++cc)
        part = fmaf(gelu_f(t[i][cc]), w2s[jt + 32 * cc], part);
      #pragma unroll
      for (int off = 1; off < 32; off <<= 1)
        part += __shfl_xor(part, off, 64);
      if (jt == 0) out[r0 + rg + 8 * i] = part + b2v;
    }
  }
}

extern "C" void kernel_launch(void* const* d_in, const int* in_sizes, int n_in,
                              void* d_out, int out_size, void* d_ws, size_t ws_size,
                              hipStream_t stream) {
  (void)in_sizes; (void)n_in; (void)out_size; (void)ws_size;
  const float* x      = (const float*)d_in[0];
  const float* fcin_w = (const float*)d_in[1];
  const float* fcin_b = (const float*)d_in[2];
  const float* wr     = (const float*)d_in[3];
  const float* wi     = (const float*)d_in[4];
  const float* ww     = (const float*)d_in[5];
  const float* wb     = (const float*)d_in[6];
  const float* fc1_w  = (const float*)d_in[7];
  const float* fc1_b  = (const float*)d_in[8];
  const float* fc2_w  = (const float*)d_in[9];
  const float* fc2_b  = (const float*)d_in[10];
  float* out = (float*)d_out;

  // workspace layout (floats): total ~24.6M floats (~99 MB)
  float*  hA = (float*)d_ws;              // 16,777,216
  float2* A1 = (float2*)(hA + 16777216);  // 2,097,152 float2 (A1 fwd / T bwd alias)
  float*  Ar = (float*)(A1 + 2097152);    // 262,144
  float*  Ai = Ar + 262144;               // 262,144
  float*  Br = Ai + 262144;               // 1,048,576
  float*  Bi = Br + 1048576;              // 1,048,576
  float2* Cp = (float2*)(Bi + 1048576);   // 524,288 float2 (2 K-split partials)

  k_fc_in<<<65536, 256, 0, stream>>>(x, fcin_w, fcin_b, hA);
  for (int l = 0; l < 4; ++l) {
    k_prep<<<4096, 256, 0, stream>>>(wr + (size_t)l * 8388608,
                                     wi + (size_t)l * 8388608, Br, Bi);
    k_dft_y<<<2048, 256, 0, stream>>>(hA, A1);
    k_dft_x<<<dim3(16, 16, 2), 256, 0, stream>>>(A1, Ar, Ai);
    k_gemm<<<dim3(32, 8, 2), 256, 0, stream>>>(Ar, Ai, Br, Bi, Cp);
    k_ifft_y<<<256, 256, 0, stream>>>(Cp, A1);     // A1 now holds T
    k_layer_out<<<2048, 256, 0, stream>>>(hA, A1, ww + (size_t)l * 4096,
                                          wb + (size_t)l * 64, hA);
  }
  k_final<<<1024, 256, 0, stream>>>(hA, fc1_w, fc1_b, fc2_w, fc2_b, out);
}

// Round 3
// 1225.662 us; speedup vs baseline: 1.5083x; 1.5083x over previous
//
#include <hip/hip_runtime.h>
#include <math.h>

// Sizes: B=16, H=128, W=128, C=64, MODES=16, SCHMIDT=8, N_LAYERS=4
// h buffer: 16*128*128*64 = 16,777,216 floats (67 MB), updated in place per layer.

#define TWO_PI_128 0.049087385212340517f   // 2*pi/128
#define PI_4       0.78539816339744831f    // pi/4

__device__ __forceinline__ float gelu_f(float v) {
  float v2 = v * v;
  float u = 0.7978845608028654f * v * fmaf(0.044715f, v2, 1.0f);
  return 0.5f * v * (1.0f + tanhf(u));
}

// h[pix][c] = sum_k x[pix][k] * w[k][c] + b[c]
__global__ __launch_bounds__(256) void k_fc_in(const float* __restrict__ x,
    const float* __restrict__ w, const float* __restrict__ b,
    float* __restrict__ h) {
  int idx = blockIdx.x * 256 + threadIdx.x;   // over NPIX*64
  int pix = idx >> 6, c = idx & 63;
  float acc = b[c];
  acc = fmaf(x[pix * 3 + 0], w[c], acc);
  acc = fmaf(x[pix * 3 + 1], w[64 + c], acc);
  acc = fmaf(x[pix * 3 + 2], w[128 + c], acc);
  h[idx] = acc;
}

// Fold Schmidt sum + 1/sqrt(8) + 1/(128*128) into complex weight,
// laid out for GEMM: Br/Bi[(n*64+c)*1024 + (m*64+o)]
__global__ __launch_bounds__(256) void k_prep(const float* __restrict__ wr,
    const float* __restrict__ wi, float* __restrict__ Br, float* __restrict__ Bi) {
  int t = blockIdx.x * 256 + threadIdx.x;     // linear over (m,n,c,o), o innermost
  int o = t & 63, c = (t >> 6) & 63, n = (t >> 12) & 15, m = t >> 16;
  const float4* pr = (const float4*)(wr) + (size_t)t * 2;
  float4 a = pr[0], d = pr[1];
  float sr = ((a.x + a.y) + (a.z + a.w)) + ((d.x + d.y) + (d.z + d.w));
  const float4* pi = (const float4*)(wi) + (size_t)t * 2;
  a = pi[0]; d = pi[1];
  float si = ((a.x + a.y) + (a.z + a.w)) + ((d.x + d.y) + (d.z + d.w));
  const float scale = 0.35355339059327373f / 16384.0f;  // 1/(sqrt(8)*128*128)
  int k = n * 64 + c, j = m * 64 + o;
  Br[k * 1024 + j] = sr * scale;
  Bi[k * 1024 + j] = si * scale;
}

// Forward truncated DFT along y (W axis): A1[b][x][ky][c], ky<16
__global__ __launch_bounds__(256) void k_dft_y(const float* __restrict__ h,
                                               float2* __restrict__ A1) {
  __shared__ float sh[128 * 64];
  int bx = blockIdx.x;                        // b*128 + x
  const float* src = h + (size_t)bx * 8192;
  for (int i = threadIdx.x; i < 8192; i += 256) sh[i] = src[i];
  __syncthreads();
  int c = threadIdx.x & 63, kg = threadIdx.x >> 6;
  float cs[4], sn[4], wr_[4], wi_[4], sr[4], si[4];
  #pragma unroll
  for (int q = 0; q < 4; ++q) {
    int ky = kg + 4 * q;
    __sincosf(-TWO_PI_128 * (float)ky, &sn[q], &cs[q]);
    wr_[q] = 1.f; wi_[q] = 0.f; sr[q] = 0.f; si[q] = 0.f;
  }
  for (int y = 0; y < 128; ++y) {
    float hv = sh[y * 64 + c];
    #pragma unroll
    for (int q = 0; q < 4; ++q) {
      sr[q] = fmaf(hv, wr_[q], sr[q]);
      si[q] = fmaf(hv, wi_[q], si[q]);
      float nw = wr_[q] * cs[q] - wi_[q] * sn[q];
      wi_[q] = fmaf(wi_[q], cs[q], wr_[q] * sn[q]);
      wr_[q] = nw;
    }
  }
  #pragma unroll
  for (int q = 0; q < 4; ++q) {
    int ky = kg + 4 * q;
    A1[((size_t)bx * 16 + ky) * 64 + c] = make_float2(sr[q], si[q]);
  }
}

// Forward truncated DFT along x (H axis): rows (b*16+kx), cols (ky*64+c)
__global__ __launch_bounds__(256) void k_dft_x(const float2* __restrict__ A1,
    float* __restrict__ Ar, float* __restrict__ Ai) {
  __shared__ float2 sh[128 * 32];
  int b = blockIdx.x, ky = blockIdx.y, ch = blockIdx.z;
  int c0 = ch * 32;
  for (int i = threadIdx.x; i < 4096; i += 256) {
    int xx = i >> 5, cl = i & 31;
    sh[i] = A1[(((size_t)b * 128 + xx) * 16 + ky) * 64 + c0 + cl];
  }
  __syncthreads();
  int cl = threadIdx.x & 31, kxg = threadIdx.x >> 5;
  float cs[2], sn[2], wr_[2], wi_[2], sr[2], si[2];
  #pragma unroll
  for (int q = 0; q < 2; ++q) {
    int kx = kxg + 8 * q;
    __sincosf(-TWO_PI_128 * (float)kx, &sn[q], &cs[q]);
    wr_[q] = 1.f; wi_[q] = 0.f; sr[q] = 0.f; si[q] = 0.f;
  }
  for (int xx = 0; xx < 128; ++xx) {
    float2 v = sh[xx * 32 + cl];
    #pragma unroll
    for (int q = 0; q < 2; ++q) {
      sr[q] = fmaf(v.x, wr_[q], sr[q]); sr[q] = fmaf(-v.y, wi_[q], sr[q]);
      si[q] = fmaf(v.x, wi_[q], si[q]); si[q] = fmaf(v.y, wr_[q], si[q]);
      float nw = wr_[q] * cs[q] - wi_[q] * sn[q];
      wi_[q] = fmaf(wi_[q], cs[q], wr_[q] * sn[q]);
      wr_[q] = nw;
    }
  }
  #pragma unroll
  for (int q = 0; q < 2; ++q) {
    int kx = kxg + 8 * q;
    int row = b * 16 + kx, col = ky * 64 + c0 + cl;
    Ar[row * 1024 + col] = sr[q];
    Ai[row * 1024 + col] = si[q];
  }
}

// Complex GEMM: C[256][1024] = A[256][1024] * B[1024][1024], K split in 2 (blockIdx.z)
__global__ __launch_bounds__(256) void k_gemm(const float* __restrict__ Ar,
    const float* __restrict__ Ai, const float* __restrict__ Br,
    const float* __restrict__ Bi, float2* __restrict__ Cp) {
  __shared__ float2 As[32][33];
  __shared__ float2 Bs[32][34];
  int tx = threadIdx.x & 15, ty = threadIdx.x >> 4;
  int row0 = blockIdx.y * 32, col0 = blockIdx.x * 32, kbase = blockIdx.z * 512;
  float cr00 = 0, cr01 = 0, cr10 = 0, cr11 = 0;
  float ci00 = 0, ci01 = 0, ci10 = 0, ci11 = 0;
  for (int kt = 0; kt < 512; kt += 32) {
    int k0 = kbase + kt;
    for (int i = threadIdx.x; i < 1024; i += 256) {
      int r = i >> 5, kk = i & 31;
      int gi = (row0 + r) * 1024 + k0 + kk;
      As[r][kk] = make_float2(Ar[gi], Ai[gi]);
    }
    for (int i = threadIdx.x; i < 1024; i += 256) {
      int kk = i >> 5, j = i & 31;
      int gi = (k0 + kk) * 1024 + col0 + j;
      Bs[kk][j] = make_float2(Br[gi], Bi[gi]);
    }
    __syncthreads();
    #pragma unroll 8
    for (int kk = 0; kk < 32; ++kk) {
      float2 a0 = As[ty * 2][kk], a1 = As[ty * 2 + 1][kk];
      float2 b0 = Bs[kk][tx * 2], b1 = Bs[kk][tx * 2 + 1];
      cr00 = fmaf(a0.x, b0.x, cr00); cr00 = fmaf(-a0.y, b0.y, cr00);
      ci00 = fmaf(a0.x, b0.y, ci00); ci00 = fmaf(a0.y, b0.x, ci00);
      cr01 = fmaf(a0.x, b1.x, cr01); cr01 = fmaf(-a0.y, b1.y, cr01);
      ci01 = fmaf(a0.x, b1.y, ci01); ci01 = fmaf(a0.y, b1.x, ci01);
      cr10 = fmaf(a1.x, b0.x, cr10); cr10 = fmaf(-a1.y, b0.y, cr10);
      ci10 = fmaf(a1.x, b0.y, ci10); ci10 = fmaf(a1.y, b0.x, ci10);
      cr11 = fmaf(a1.x, b1.x, cr11); cr11 = fmaf(-a1.y, b1.y, cr11);
      ci11 = fmaf(a1.x, b1.y, ci11); ci11 = fmaf(a1.y, b1.x, ci11);
    }
    __syncthreads();
  }
  int r = row0 + ty * 2, jj = col0 + tx * 2;
  size_t base = ((size_t)blockIdx.z * 256 + r) * 1024 + jj;
  Cp[base]        = make_float2(cr00, ci00);
  Cp[base + 1]    = make_float2(cr01, ci01);
  Cp[base + 1024] = make_float2(cr10, ci10);
  Cp[base + 1025] = make_float2(cr11, ci11);
}

// Inverse DFT along the W-frequency axis m -> y. Sums the two K-split partials.
// T layout: [b][y][kx][c]
__global__ __launch_bounds__(256) void k_ifft_y(const float2* __restrict__ Cp,
                                                float2* __restrict__ T) {
  __shared__ float2 Cl[1024];
  int b = blockIdx.x >> 4, kx = blockIdx.x & 15;
  int row = b * 16 + kx;
  for (int i = threadIdx.x; i < 1024; i += 256) {
    float2 u = Cp[(size_t)row * 1024 + i];
    float2 v = Cp[(size_t)(256 + row) * 1024 + i];
    Cl[i] = make_float2(u.x + v.x, u.y + v.y);
  }
  __syncthreads();
  int c = threadIdx.x & 63, yg = threadIdx.x >> 6;
  for (int y = yg; y < 128; y += 4) {
    float snv, csv;
    __sincosf(TWO_PI_128 * (float)y, &snv, &csv);
    float wr_ = 1.f, wi_ = 0.f, sr = 0.f, si = 0.f;
    #pragma unroll
    for (int ky = 0; ky < 16; ++ky) {
      float2 v = Cl[ky * 64 + c];
      sr = fmaf(v.x, wr_, sr); sr = fmaf(-v.y, wi_, sr);
      si = fmaf(v.x, wi_, si); si = fmaf(v.y, wr_, si);
      float nw = wr_ * csv - wi_ * snv;
      wi_ = fmaf(wi_, csv, wr_ * snv);
      wr_ = nw;
    }
    T[(((size_t)b * 128 + y) * 16 + kx) * 64 + c] = make_float2(sr, si);
  }
}

// Fused: inverse DFT along kx -> x (real part) + pointwise h@ww + wb + gelu.
// Block (b,y): reads/writes exactly the h elements at fixed (b,y) -> in-place safe.
__global__ __launch_bounds__(256) void k_layer_out(const float* hin,
    const float2* __restrict__ T, const float* __restrict__ ww,
    const float* __restrict__ wb, float* hout) {
  __shared__ alignas(16) float hl[128 * 68];
  __shared__ alignas(16) float wwT[64 * 68];
  __shared__ float2 Tl[1024];
  int b = blockIdx.x >> 7, y = blockIdx.x & 127;
  for (int i = threadIdx.x; i < 8192; i += 256) {
    int xx = i >> 6, c = i & 63;
    hl[xx * 68 + c] = hin[(((size_t)b * 128 + xx) * 128 + y) * 64 + c];
  }
  for (int i = threadIdx.x; i < 4096; i += 256) {
    int k = i >> 6, c = i & 63;
    wwT[c * 68 + k] = ww[i];
  }
  for (int i = threadIdx.x; i < 1024; i += 256)
    Tl[i] = T[((size_t)b * 128 + y) * 1024 + i];
  __syncthreads();
  int ct = threadIdx.x & 15, xg = threadIdx.x >> 4;   // c = ct+16*cc, x = xg+16*j
  float acc[8][4];
  #pragma unroll
  for (int cc = 0; cc < 4; ++cc) {
    float bv = wb[ct + 16 * cc];
    #pragma unroll
    for (int j = 0; j < 8; ++j) acc[j][cc] = bv;
  }
  // x1: real part of sum_kx T[kx][c] * e^{+2pi i kx x/128}
  for (int kx = 0; kx < 16; ++kx) {
    float tr[4], ti[4];
    #pragma unroll
    for (int cc = 0; cc < 4; ++cc) {
      float2 v = Tl[kx * 64 + ct + 16 * cc];
      tr[cc] = v.x; ti[cc] = v.y;
    }
    float s0v, c0v, sst, cst;
    __sincosf(TWO_PI_128 * (float)(kx * xg), &s0v, &c0v);
    __sincosf(PI_4 * (float)kx, &sst, &cst);
    float wr_ = c0v, wi_ = s0v;
    #pragma unroll
    for (int j = 0; j < 8; ++j) {
      #pragma unroll
      for (int cc = 0; cc < 4; ++cc) {
        acc[j][cc] = fmaf(tr[cc], wr_, acc[j][cc]);
        acc[j][cc] = fmaf(-ti[cc], wi_, acc[j][cc]);
      }
      float nw = wr_ * cst - wi_ * sst;
      wi_ = fmaf(wi_, cst, wr_ * sst);
      wr_ = nw;
    }
  }
  // x2: h @ ww
  for (int kq = 0; kq < 64; kq += 4) {
    float4 wv[4];
    #pragma unroll
    for (int cc = 0; cc < 4; ++cc)
      wv[cc] = *(const float4*)&wwT[(ct + 16 * cc) * 68 + kq];
    #pragma unroll
    for (int j = 0; j < 8; ++j) {
      float4 hv = *(const float4*)&hl[(xg + 16 * j) * 68 + kq];
      #pragma unroll
      for (int cc = 0; cc < 4; ++cc) {
        acc[j][cc] = fmaf(hv.x, wv[cc].x, acc[j][cc]);
        acc[j][cc] = fmaf(hv.y, wv[cc].y, acc[j][cc]);
        acc[j][cc] = fmaf(hv.z, wv[cc].z, acc[j][cc]);
        acc[j][cc] = fmaf(hv.w, wv[cc].w, acc[j][cc]);
      }
    }
  }
  #pragma unroll
  for (int j = 0; j < 8; ++j) {
    int xx = xg + 16 * j;
    size_t base = (((size_t)b * 128 + xx) * 128 + y) * 64 + ct;
    #pragma unroll
    for (int cc = 0; cc < 4; ++cc)
      hout[base + 16 * cc] = gelu_f(acc[j][cc]);
  }
}

// Fused fc1 + gelu + fc2.
// One tile per block (NO outer chunk loop -- the R0 version's chunk loop got
// unrolled, spilled 256+ VGPRs, and wrote 725 MB of scratch = 700 us).
// Block = 64 rows x 128 j; thread tile = 4 rows x 8 j (32 acc + 16 frag regs).
// Grid MUST be 4096 (4096*64 = 262144 rows) -- R1 failed with 1024.
__global__ __launch_bounds__(256) void k_final(const float* __restrict__ h,
    const float* __restrict__ w1, const float* __restrict__ b1,
    const float* __restrict__ w2, const float* __restrict__ b2,
    float* __restrict__ out) {
  __shared__ alignas(16) float w1T[128 * 68];   // w1T[j][k]
  __shared__ alignas(16) float hl[64 * 68];     // hl[r][k]
  __shared__ float b1s[128];
  __shared__ float w2s[128];
  for (int i = threadIdx.x; i < 8192; i += 256) {
    int k = i >> 7, j = i & 127;
    w1T[j * 68 + k] = w1[i];
  }
  if (threadIdx.x < 128) {
    b1s[threadIdx.x] = b1[threadIdx.x];
    w2s[threadIdx.x] = w2[threadIdx.x];
  }
  int r0 = blockIdx.x * 64;
  for (int i = threadIdx.x; i < 1024; i += 256) {
    int r = i >> 4, kq = (i & 15) * 4;          // coalesced float4 row loads
    float4 v = *(const float4*)&h[(size_t)(r0 + r) * 64 + kq];
    *(float4*)&hl[r * 68 + kq] = v;
  }
  __syncthreads();
  int jt = threadIdx.x & 15, rg = threadIdx.x >> 4;  // j = jt+16*cc, r = rg+16*ii
  float acc[4][8];
  #pragma unroll
  for (int cc = 0; cc < 8; ++cc) {
    float bv = b1s[jt + 16 * cc];
    #pragma unroll
    for (int ii = 0; ii < 4; ++ii) acc[ii][cc] = bv;
  }
  #pragma unroll 1
  for (int kq = 0; kq < 64; kq += 4) {
    float4 hv[4];
    #pragma unroll
    for (int ii = 0; ii < 4; ++ii)
      hv[ii] = *(const float4*)&hl[(rg + 16 * ii) * 68 + kq];
    #pragma unroll
    for (int cc = 0; cc < 8; ++cc) {
      float4 wv = *(const float4*)&w1T[(jt + 16 * cc) * 68 + kq];
      #pragma unroll
      for (int ii = 0; ii < 4; ++ii) {
        acc[ii][cc] = fmaf(hv[ii].x, wv.x, acc[ii][cc]);
        acc[ii][cc] = fmaf(hv[ii].y, wv.y, acc[ii][cc]);
        acc[ii][cc] = fmaf(hv[ii].z, wv.z, acc[ii][cc]);
        acc[ii][cc] = fmaf(hv[ii].w, wv.w, acc[ii][cc]);
      }
    }
  }
  float b2v = b2[0];
  #pragma unroll
  for (int ii = 0; ii < 4; ++ii) {
    float part = 0.f;
    #pragma unroll
    for (int cc = 0; cc < 8; ++cc)
      part = fmaf(gelu_f(acc[ii][cc]), w2s[jt + 16 * cc], part);
    part += __shfl_xor(part, 1, 64);
    part += __shfl_xor(part, 2, 64);
    part += __shfl_xor(part, 4, 64);
    part += __shfl_xor(part, 8, 64);
    if (jt == 0) out[r0 + rg + 16 * ii] = part + b2v;
  }
}

extern "C" void kernel_launch(void* const* d_in, const int* in_sizes, int n_in,
                              void* d_out, int out_size, void* d_ws, size_t ws_size,
                              hipStream_t stream) {
  (void)in_sizes; (void)n_in; (void)out_size; (void)ws_size;
  const float* x      = (const float*)d_in[0];
  const float* fcin_w = (const float*)d_in[1];
  const float* fcin_b = (const float*)d_in[2];
  const float* wr     = (const float*)d_in[3];
  const float* wi     = (const float*)d_in[4];
  const float* ww     = (const float*)d_in[5];
  const float* wb     = (const float*)d_in[6];
  const float* fc1_w  = (const float*)d_in[7];
  const float* fc1_b  = (const float*)d_in[8];
  const float* fc2_w  = (const float*)d_in[9];
  const float* fc2_b  = (const float*)d_in[10];
  float* out = (float*)d_out;

  // workspace layout (floats): total ~24.6M floats (~99 MB)
  float*  hA = (float*)d_ws;              // 16,777,216
  float2* A1 = (float2*)(hA + 16777216);  // 2,097,152 float2 (A1 fwd / T bwd alias)
  float*  Ar = (float*)(A1 + 2097152);    // 262,144
  float*  Ai = Ar + 262144;               // 262,144
  float*  Br = Ai + 262144;               // 1,048,576
  float*  Bi = Br + 1048576;              // 1,048,576
  float2* Cp = (float2*)(Bi + 1048576);   // 524,288 float2 (2 K-split partials)

  k_fc_in<<<65536, 256, 0, stream>>>(x, fcin_w, fcin_b, hA);
  for (int l = 0; l < 4; ++l) {
    k_prep<<<4096, 256, 0, stream>>>(wr + (size_t)l * 8388608,
                                     wi + (size_t)l * 8388608, Br, Bi);
    k_dft_y<<<2048, 256, 0, stream>>>(hA, A1);
    k_dft_x<<<dim3(16, 16, 2), 256, 0, stream>>>(A1, Ar, Ai);
    k_gemm<<<dim3(32, 8, 2), 256, 0, stream>>>(Ar, Ai, Br, Bi, Cp);
    k_ifft_y<<<256, 256, 0, stream>>>(Cp, A1);     // A1 now holds T
    k_layer_out<<<2048, 256, 0, stream>>>(hA, A1, ww + (size_t)l * 4096,
                                          wb + (size_t)l * 64, hA);
  }
  k_final<<<4096, 256, 0, stream>>>(hA, fc1_w, fc1_b, fc2_w, fc2_b, out);
}

// Round 4
// 1187.829 us; speedup vs baseline: 1.5564x; 1.0319x over previous
//
#include <hip/hip_runtime.h>
#include <math.h>

// Sizes: B=16, H=128, W=128, C=64, MODES=16, SCHMIDT=8, N_LAYERS=4
// h buffer: 16*128*128*64 = 16,777,216 floats (67 MB), updated in place per layer.

#define TWO_PI_128 0.049087385212340517f   // 2*pi/128
#define PI_4       0.78539816339744831f    // pi/4

// gelu(v) = 0.5 v (1 + tanh(u)), u = 0.79788456 v (1 + 0.044715 v^2)
//         = v * (1 - 1/(e^{2u} + 1))   -- ~10 VALU vs ~35 for libm tanhf
__device__ __forceinline__ float gelu_f(float v) {
  float ex = 1.5957691216057308f * v * fmaf(0.044715f, v * v, 1.0f);  // 2u
  float e = __expf(fminf(ex, 30.0f));      // clamp: avoid inf -> NaN in rcp
  float r = __builtin_amdgcn_rcpf(e + 1.0f);
  return fmaf(-v, r, v);
}

// h[pix][c] = sum_k x[pix][k] * w[k][c] + b[c]
__global__ __launch_bounds__(256) void k_fc_in(const float* __restrict__ x,
    const float* __restrict__ w, const float* __restrict__ b,
    float* __restrict__ h) {
  int idx = blockIdx.x * 256 + threadIdx.x;   // over NPIX*64
  int pix = idx >> 6, c = idx & 63;
  float acc = b[c];
  acc = fmaf(x[pix * 3 + 0], w[c], acc);
  acc = fmaf(x[pix * 3 + 1], w[64 + c], acc);
  acc = fmaf(x[pix * 3 + 2], w[128 + c], acc);
  h[idx] = acc;
}

// Fold Schmidt sum + 1/sqrt(8) + 1/(128*128) into complex weight,
// laid out for GEMM: Br/Bi[(n*64+c)*1024 + (m*64+o)]
__global__ __launch_bounds__(256) void k_prep(const float* __restrict__ wr,
    const float* __restrict__ wi, float* __restrict__ Br, float* __restrict__ Bi) {
  int t = blockIdx.x * 256 + threadIdx.x;     // linear over (m,n,c,o), o innermost
  int o = t & 63, c = (t >> 6) & 63, n = (t >> 12) & 15, m = t >> 16;
  const float4* pr = (const float4*)(wr) + (size_t)t * 2;
  float4 a = pr[0], d = pr[1];
  float sr = ((a.x + a.y) + (a.z + a.w)) + ((d.x + d.y) + (d.z + d.w));
  const float4* pi = (const float4*)(wi) + (size_t)t * 2;
  a = pi[0]; d = pi[1];
  float si = ((a.x + a.y) + (a.z + a.w)) + ((d.x + d.y) + (d.z + d.w));
  const float scale = 0.35355339059327373f / 16384.0f;  // 1/(sqrt(8)*128*128)
  int k = n * 64 + c, j = m * 64 + o;
  Br[k * 1024 + j] = sr * scale;
  Bi[k * 1024 + j] = si * scale;
}

// Forward truncated DFT along y (W axis): A1[b][x][ky][c], ky<16
__global__ __launch_bounds__(256) void k_dft_y(const float* __restrict__ h,
                                               float2* __restrict__ A1) {
  __shared__ float sh[128 * 64];
  int bx = blockIdx.x;                        // b*128 + x
  const float* src = h + (size_t)bx * 8192;
  for (int i = threadIdx.x; i < 8192; i += 256) sh[i] = src[i];
  __syncthreads();
  int c = threadIdx.x & 63, kg = threadIdx.x >> 6;
  float cs[4], sn[4], wr_[4], wi_[4], sr[4], si[4];
  #pragma unroll
  for (int q = 0; q < 4; ++q) {
    int ky = kg + 4 * q;
    __sincosf(-TWO_PI_128 * (float)ky, &sn[q], &cs[q]);
    wr_[q] = 1.f; wi_[q] = 0.f; sr[q] = 0.f; si[q] = 0.f;
  }
  for (int y = 0; y < 128; ++y) {
    float hv = sh[y * 64 + c];
    #pragma unroll
    for (int q = 0; q < 4; ++q) {
      sr[q] = fmaf(hv, wr_[q], sr[q]);
      si[q] = fmaf(hv, wi_[q], si[q]);
      float nw = wr_[q] * cs[q] - wi_[q] * sn[q];
      wi_[q] = fmaf(wi_[q], cs[q], wr_[q] * sn[q]);
      wr_[q] = nw;
    }
  }
  #pragma unroll
  for (int q = 0; q < 4; ++q) {
    int ky = kg + 4 * q;
    A1[((size_t)bx * 16 + ky) * 64 + c] = make_float2(sr[q], si[q]);
  }
}

// Forward truncated DFT along x (H axis): rows (b*16+kx), cols (ky*64+c)
__global__ __launch_bounds__(256) void k_dft_x(const float2* __restrict__ A1,
    float* __restrict__ Ar, float* __restrict__ Ai) {
  __shared__ float2 sh[128 * 32];
  int b = blockIdx.x, ky = blockIdx.y, ch = blockIdx.z;
  int c0 = ch * 32;
  for (int i = threadIdx.x; i < 4096; i += 256) {
    int xx = i >> 5, cl = i & 31;
    sh[i] = A1[(((size_t)b * 128 + xx) * 16 + ky) * 64 + c0 + cl];
  }
  __syncthreads();
  int cl = threadIdx.x & 31, kxg = threadIdx.x >> 5;
  float cs[2], sn[2], wr_[2], wi_[2], sr[2], si[2];
  #pragma unroll
  for (int q = 0; q < 2; ++q) {
    int kx = kxg + 8 * q;
    __sincosf(-TWO_PI_128 * (float)kx, &sn[q], &cs[q]);
    wr_[q] = 1.f; wi_[q] = 0.f; sr[q] = 0.f; si[q] = 0.f;
  }
  for (int xx = 0; xx < 128; ++xx) {
    float2 v = sh[xx * 32 + cl];
    #pragma unroll
    for (int q = 0; q < 2; ++q) {
      sr[q] = fmaf(v.x, wr_[q], sr[q]); sr[q] = fmaf(-v.y, wi_[q], sr[q]);
      si[q] = fmaf(v.x, wi_[q], si[q]); si[q] = fmaf(v.y, wr_[q], si[q]);
      float nw = wr_[q] * cs[q] - wi_[q] * sn[q];
      wi_[q] = fmaf(wi_[q], cs[q], wr_[q] * sn[q]);
      wr_[q] = nw;
    }
  }
  #pragma unroll
  for (int q = 0; q < 2; ++q) {
    int kx = kxg + 8 * q;
    int row = b * 16 + kx, col = ky * 64 + c0 + cl;
    Ar[row * 1024 + col] = sr[q];
    Ai[row * 1024 + col] = si[q];
  }
}

// Complex GEMM: C[256][1024] = A[256][1024] * B[1024][1024], K split in 2 (blockIdx.z)
__global__ __launch_bounds__(256) void k_gemm(const float* __restrict__ Ar,
    const float* __restrict__ Ai, const float* __restrict__ Br,
    const float* __restrict__ Bi, float2* __restrict__ Cp) {
  __shared__ float2 As[32][33];
  __shared__ float2 Bs[32][34];
  int tx = threadIdx.x & 15, ty = threadIdx.x >> 4;
  int row0 = blockIdx.y * 32, col0 = blockIdx.x * 32, kbase = blockIdx.z * 512;
  float cr00 = 0, cr01 = 0, cr10 = 0, cr11 = 0;
  float ci00 = 0, ci01 = 0, ci10 = 0, ci11 = 0;
  for (int kt = 0; kt < 512; kt += 32) {
    int k0 = kbase + kt;
    for (int i = threadIdx.x; i < 1024; i += 256) {
      int r = i >> 5, kk = i & 31;
      int gi = (row0 + r) * 1024 + k0 + kk;
      As[r][kk] = make_float2(Ar[gi], Ai[gi]);
    }
    for (int i = threadIdx.x; i < 1024; i += 256) {
      int kk = i >> 5, j = i & 31;
      int gi = (k0 + kk) * 1024 + col0 + j;
      Bs[kk][j] = make_float2(Br[gi], Bi[gi]);
    }
    __syncthreads();
    #pragma unroll 8
    for (int kk = 0; kk < 32; ++kk) {
      float2 a0 = As[ty * 2][kk], a1 = As[ty * 2 + 1][kk];
      float2 b0 = Bs[kk][tx * 2], b1 = Bs[kk][tx * 2 + 1];
      cr00 = fmaf(a0.x, b0.x, cr00); cr00 = fmaf(-a0.y, b0.y, cr00);
      ci00 = fmaf(a0.x, b0.y, ci00); ci00 = fmaf(a0.y, b0.x, ci00);
      cr01 = fmaf(a0.x, b1.x, cr01); cr01 = fmaf(-a0.y, b1.y, cr01);
      ci01 = fmaf(a0.x, b1.y, ci01); ci01 = fmaf(a0.y, b1.x, ci01);
      cr10 = fmaf(a1.x, b0.x, cr10); cr10 = fmaf(-a1.y, b0.y, cr10);
      ci10 = fmaf(a1.x, b0.y, ci10); ci10 = fmaf(a1.y, b0.x, ci10);
      cr11 = fmaf(a1.x, b1.x, cr11); cr11 = fmaf(-a1.y, b1.y, cr11);
      ci11 = fmaf(a1.x, b1.y, ci11); ci11 = fmaf(a1.y, b1.x, ci11);
    }
    __syncthreads();
  }
  int r = row0 + ty * 2, jj = col0 + tx * 2;
  size_t base = ((size_t)blockIdx.z * 256 + r) * 1024 + jj;
  Cp[base]        = make_float2(cr00, ci00);
  Cp[base + 1]    = make_float2(cr01, ci01);
  Cp[base + 1024] = make_float2(cr10, ci10);
  Cp[base + 1025] = make_float2(cr11, ci11);
}

// Inverse DFT along the W-frequency axis m -> y. Sums the two K-split partials.
// T layout: [b][y][kx][c]
__global__ __launch_bounds__(256) void k_ifft_y(const float2* __restrict__ Cp,
                                                float2* __restrict__ T) {
  __shared__ float2 Cl[1024];
  int b = blockIdx.x >> 4, kx = blockIdx.x & 15;
  int row = b * 16 + kx;
  for (int i = threadIdx.x; i < 1024; i += 256) {
    float2 u = Cp[(size_t)row * 1024 + i];
    float2 v = Cp[(size_t)(256 + row) * 1024 + i];
    Cl[i] = make_float2(u.x + v.x, u.y + v.y);
  }
  __syncthreads();
  int c = threadIdx.x & 63, yg = threadIdx.x >> 6;
  for (int y = yg; y < 128; y += 4) {
    float snv, csv;
    __sincosf(TWO_PI_128 * (float)y, &snv, &csv);
    float wr_ = 1.f, wi_ = 0.f, sr = 0.f, si = 0.f;
    #pragma unroll
    for (int ky = 0; ky < 16; ++ky) {
      float2 v = Cl[ky * 64 + c];
      sr = fmaf(v.x, wr_, sr); sr = fmaf(-v.y, wi_, sr);
      si = fmaf(v.x, wi_, si); si = fmaf(v.y, wr_, si);
      float nw = wr_ * csv - wi_ * snv;
      wi_ = fmaf(wi_, csv, wr_ * snv);
      wr_ = nw;
    }
    T[(((size_t)b * 128 + y) * 16 + kx) * 64 + c] = make_float2(sr, si);
  }
}

// Fused: inverse DFT along kx -> x (real part) + pointwise h@ww + wb + gelu.
// Block (b,y): reads/writes exactly the h elements at fixed (b,y) -> in-place safe.
// Tl staging removed (T read from global, L2-hot): LDS 59->52 KB = 3 blocks/CU.
__global__ __launch_bounds__(256) void k_layer_out(const float* hin,
    const float2* __restrict__ T, const float* __restrict__ ww,
    const float* __restrict__ wb, float* hout) {
  __shared__ alignas(16) float hl[128 * 68];
  __shared__ alignas(16) float wwT[64 * 68];
  int b = blockIdx.x >> 7, y = blockIdx.x & 127;
  for (int i = threadIdx.x; i < 8192; i += 256) {
    int xx = i >> 6, c = i & 63;
    hl[xx * 68 + c] = hin[(((size_t)b * 128 + xx) * 128 + y) * 64 + c];
  }
  for (int i = threadIdx.x; i < 4096; i += 256) {
    int k = i >> 6, c = i & 63;
    wwT[c * 68 + k] = ww[i];
  }
  const float2* Tp = T + ((size_t)b * 128 + y) * 1024;
  __syncthreads();
  int ct = threadIdx.x & 15, xg = threadIdx.x >> 4;   // c = ct+16*cc, x = xg+16*j
  float acc[8][4];
  #pragma unroll
  for (int cc = 0; cc < 4; ++cc) {
    float bv = wb[ct + 16 * cc];
    #pragma unroll
    for (int j = 0; j < 8; ++j) acc[j][cc] = bv;
  }
  // x1: real part of sum_kx T[kx][c] * e^{+2pi i kx x/128}
  for (int kx = 0; kx < 16; ++kx) {
    float tr[4], ti[4];
    #pragma unroll
    for (int cc = 0; cc < 4; ++cc) {
      float2 v = Tp[kx * 64 + ct + 16 * cc];
      tr[cc] = v.x; ti[cc] = v.y;
    }
    float s0v, c0v, sst, cst;
    __sincosf(TWO_PI_128 * (float)(kx * xg), &s0v, &c0v);
    __sincosf(PI_4 * (float)kx, &sst, &cst);
    float wr_ = c0v, wi_ = s0v;
    #pragma unroll
    for (int j = 0; j < 8; ++j) {
      #pragma unroll
      for (int cc = 0; cc < 4; ++cc) {
        acc[j][cc] = fmaf(tr[cc], wr_, acc[j][cc]);
        acc[j][cc] = fmaf(-ti[cc], wi_, acc[j][cc]);
      }
      float nw = wr_ * cst - wi_ * sst;
      wi_ = fmaf(wi_, cst, wr_ * sst);
      wr_ = nw;
    }
  }
  // x2: h @ ww
  for (int kq = 0; kq < 64; kq += 4) {
    float4 wv[4];
    #pragma unroll
    for (int cc = 0; cc < 4; ++cc)
      wv[cc] = *(const float4*)&wwT[(ct + 16 * cc) * 68 + kq];
    #pragma unroll
    for (int j = 0; j < 8; ++j) {
      float4 hv = *(const float4*)&hl[(xg + 16 * j) * 68 + kq];
      #pragma unroll
      for (int cc = 0; cc < 4; ++cc) {
        acc[j][cc] = fmaf(hv.x, wv[cc].x, acc[j][cc]);
        acc[j][cc] = fmaf(hv.y, wv[cc].y, acc[j][cc]);
        acc[j][cc] = fmaf(hv.z, wv[cc].z, acc[j][cc]);
        acc[j][cc] = fmaf(hv.w, wv[cc].w, acc[j][cc]);
      }
    }
  }
  #pragma unroll
  for (int j = 0; j < 8; ++j) {
    int xx = xg + 16 * j;
    size_t base = (((size_t)b * 128 + xx) * 128 + y) * 64 + ct;
    #pragma unroll
    for (int cc = 0; cc < 4; ++cc)
      hout[base + 16 * cc] = gelu_f(acc[j][cc]);
  }
}

// Fused fc1 + gelu + fc2.
// 8x8 thread tile (128 rows x 128 j per block, grid 2048): doubles fma per
// LDS-read vs the 4x8 tile. acc 64 + hv 32 regs, no outer loop -> no spill.
__global__ __launch_bounds__(256) void k_final(const float* __restrict__ h,
    const float* __restrict__ w1, const float* __restrict__ b1,
    const float* __restrict__ w2, const float* __restrict__ b2,
    float* __restrict__ out) {
  __shared__ alignas(16) float w1T[128 * 68];   // w1T[j][k]
  __shared__ alignas(16) float hl[128 * 68];    // hl[r][k]
  __shared__ float b1s[128];
  __shared__ float w2s[128];
  for (int i = threadIdx.x; i < 8192; i += 256) {
    int k = i >> 7, j = i & 127;
    w1T[j * 68 + k] = w1[i];
  }
  if (threadIdx.x < 128) {
    b1s[threadIdx.x] = b1[threadIdx.x];
    w2s[threadIdx.x] = w2[threadIdx.x];
  }
  int r0 = blockIdx.x * 128;
  for (int i = threadIdx.x; i < 2048; i += 256) {
    int r = i >> 4, kq = (i & 15) * 4;          // coalesced float4 row loads
    float4 v = *(const float4*)&h[(size_t)(r0 + r) * 64 + kq];
    *(float4*)&hl[r * 68 + kq] = v;
  }
  __syncthreads();
  int jt = threadIdx.x & 15, rg = threadIdx.x >> 4;  // j = jt+16*cc, r = rg+16*ii
  float acc[8][8];   // [ii][cc]
  #pragma unroll
  for (int cc = 0; cc < 8; ++cc) {
    float bv = b1s[jt + 16 * cc];
    #pragma unroll
    for (int ii = 0; ii < 8; ++ii) acc[ii][cc] = bv;
  }
  #pragma unroll 1
  for (int kq = 0; kq < 64; kq += 4) {
    float4 hv[8];
    #pragma unroll
    for (int ii = 0; ii < 8; ++ii)
      hv[ii] = *(const float4*)&hl[(rg + 16 * ii) * 68 + kq];
    #pragma unroll
    for (int cc = 0; cc < 8; ++cc) {
      float4 wv = *(const float4*)&w1T[(jt + 16 * cc) * 68 + kq];
      #pragma unroll
      for (int ii = 0; ii < 8; ++ii) {
        acc[ii][cc] = fmaf(hv[ii].x, wv.x, acc[ii][cc]);
        acc[ii][cc] = fmaf(hv[ii].y, wv.y, acc[ii][cc]);
        acc[ii][cc] = fmaf(hv[ii].z, wv.z, acc[ii][cc]);
        acc[ii][cc] = fmaf(hv[ii].w, wv.w, acc[ii][cc]);
      }
    }
  }
  float b2v = b2[0];
  #pragma unroll
  for (int ii = 0; ii < 8; ++ii) {
    float part = 0.f;
    #pragma unroll
    for (int cc = 0; cc < 8; ++cc)
      part = fmaf(gelu_f(acc[ii][cc]), w2s[jt + 16 * cc], part);
    part += __shfl_xor(part, 1, 64);
    part += __shfl_xor(part, 2, 64);
    part += __shfl_xor(part, 4, 64);
    part += __shfl_xor(part, 8, 64);
    if (jt == 0) out[r0 + rg + 16 * ii] = part + b2v;
  }
}

extern "C" void kernel_launch(void* const* d_in, const int* in_sizes, int n_in,
                              void* d_out, int out_size, void* d_ws, size_t ws_size,
                              hipStream_t stream) {
  (void)in_sizes; (void)n_in; (void)out_size; (void)ws_size;
  const float* x      = (const float*)d_in[0];
  const float* fcin_w = (const float*)d_in[1];
  const float* fcin_b = (const float*)d_in[2];
  const float* wr     = (const float*)d_in[3];
  const float* wi     = (const float*)d_in[4];
  const float* ww     = (const float*)d_in[5];
  const float* wb     = (const float*)d_in[6];
  const float* fc1_w  = (const float*)d_in[7];
  const float* fc1_b  = (const float*)d_in[8];
  const float* fc2_w  = (const float*)d_in[9];
  const float* fc2_b  = (const float*)d_in[10];
  float* out = (float*)d_out;

  // workspace layout (floats): total ~24.6M floats (~99 MB)
  float*  hA = (float*)d_ws;              // 16,777,216
  float2* A1 = (float2*)(hA + 16777216);  // 2,097,152 float2 (A1 fwd / T bwd alias)
  float*  Ar = (float*)(A1 + 2097152);    // 262,144
  float*  Ai = Ar + 262144;               // 262,144
  float*  Br = Ai + 262144;               // 1,048,576
  float*  Bi = Br + 1048576;              // 1,048,576
  float2* Cp = (float2*)(Bi + 1048576);   // 524,288 float2 (2 K-split partials)

  k_fc_in<<<65536, 256, 0, stream>>>(x, fcin_w, fcin_b, hA);
  for (int l = 0; l < 4; ++l) {
    k_prep<<<4096, 256, 0, stream>>>(wr + (size_t)l * 8388608,
                                     wi + (size_t)l * 8388608, Br, Bi);
    k_dft_y<<<2048, 256, 0, stream>>>(hA, A1);
    k_dft_x<<<dim3(16, 16, 2), 256, 0, stream>>>(A1, Ar, Ai);
    k_gemm<<<dim3(32, 8, 2), 256, 0, stream>>>(Ar, Ai, Br, Bi, Cp);
    k_ifft_y<<<256, 256, 0, stream>>>(Cp, A1);     // A1 now holds T
    k_layer_out<<<2048, 256, 0, stream>>>(hA, A1, ww + (size_t)l * 4096,
                                          wb + (size_t)l * 64, hA);
  }
  k_final<<<2048, 256, 0, stream>>>(hA, fc1_w, fc1_b, fc2_w, fc2_b, out);
}